// Round 5
// baseline (439.244 us; speedup 1.0000x reference)
//
#include <hip/hip_runtime.h>

#define N_NODES 100000
#define N_EDGES 1600000

// ---- bf16 helpers (RNE) ----------------------------------------------------
__device__ __forceinline__ float bflo(unsigned u) { return __uint_as_float(u << 16); }
__device__ __forceinline__ float bfhi(unsigned u) { return __uint_as_float(u & 0xffff0000u); }
__device__ __forceinline__ unsigned short f2bf(float f) {
    unsigned u = __float_as_uint(f);
    return (unsigned short)((u + 0x7fff + ((u >> 16) & 1)) >> 16);
}
__device__ __forceinline__ unsigned packbf(float a, float b) {
    return (unsigned)f2bf(a) | ((unsigned)f2bf(b) << 16);
}

// ---------------------------------------------------------------------------
// K1: integer degree counts.  cs <- out-degree(src), cd <- in-degree(dst)
// ---------------------------------------------------------------------------
__global__ __launch_bounds__(256) void k_deg(const int* __restrict__ src,
                                             const int* __restrict__ dst,
                                             int* __restrict__ cs,
                                             int* __restrict__ cd) {
    int e = blockIdx.x * 256 + threadIdx.x;
    if (e < N_EDGES) {
        atomicAdd(&cs[src[e]], 1);
        atomicAdd(&cd[dst[e]], 1);
    }
}

// ---------------------------------------------------------------------------
// K2: per-node normalizers + CSR slot allocation.
// ---------------------------------------------------------------------------
__global__ __launch_bounds__(256) void k_alloc(const int* __restrict__ cs,
                                               const int* __restrict__ cd,
                                               int* __restrict__ gcur,
                                               int* __restrict__ start,
                                               int* __restrict__ cursor,
                                               float* __restrict__ dis,
                                               float* __restrict__ disg) {
    int i = blockIdx.x * 256 + threadIdx.x;
    if (i < N_NODES) {
        int c = cs[i], d = cd[i];
        dis[i]  = c > 0 ? rsqrtf((float)c) : 0.0f;
        disg[i] = rsqrtf((float)d + 1.0f);
        int st = atomicAdd(gcur, d);   // wave-aggregated by LLVM
        start[i]  = st;
        cursor[i] = st;
    }
}

// ---------------------------------------------------------------------------
// K3: pre-scaled bf16 rows:  xsb[s*32+f] = bf16(dis[s] * x[s*32+f])
// (dst factor of lap_w hoists out of the gather sum)
// ---------------------------------------------------------------------------
__global__ __launch_bounds__(256) void k_cvt(const float* __restrict__ x,
                                             const float* __restrict__ dis,
                                             unsigned short* __restrict__ xsb) {
    int i = blockIdx.x * 256 + threadIdx.x;
    if (i < N_NODES * 32) xsb[i] = f2bf(x[i] * dis[i >> 5]);
}

// ---------------------------------------------------------------------------
// K4: scatter edges into dst-grouped CSR — src index ONLY (4 B/edge).
// ---------------------------------------------------------------------------
__global__ __launch_bounds__(256) void k_scatter(const int* __restrict__ src,
                                                 const int* __restrict__ dst,
                                                 int* __restrict__ cursor,
                                                 int* __restrict__ csr_s) {
    int e = blockIdx.x * 256 + threadIdx.x;
    if (e < N_EDGES) {
        int pos = atomicAdd(&cursor[dst[e]], 1);
        csr_s[pos] = src[e];
    }
}

// ---------------------------------------------------------------------------
// K5: pure gather kernel:  Lxf[d] = -dis[d] * sum_e xsb[src_e]   (f32 out)
// Lean (no LDS, low VGPR) -> 32 waves/CU; lanes 0-15 even edges, 16-31 odd.
// ---------------------------------------------------------------------------
__global__ __launch_bounds__(256) void k_glx(const unsigned* __restrict__ xs32,
                                             const int* __restrict__ csr_s,
                                             const int* __restrict__ start,
                                             const int* __restrict__ cd,
                                             const float* __restrict__ dis,
                                             float* __restrict__ Lxf) {
    int tid = threadIdx.x;
    int node = blockIdx.x * 8 + (tid >> 5);
    int lane = tid & 31, half = lane >> 4, c16 = lane & 15;
    int st = start[node], cn = cd[node];

    float accx = 0.0f, accy = 0.0f;
    for (int j = 0; j < cn; j += 16) {
        int s[8]; float m[8];
#pragma unroll
        for (int u = 0; u < 8; ++u) {
            int jj = j + 2 * u + half;
            int jc = jj < cn ? jj : cn - 1;
            s[u] = csr_s[st + jc];
            m[u] = jj < cn ? 1.0f : 0.0f;
        }
        unsigned v[8];
#pragma unroll
        for (int u = 0; u < 8; ++u) v[u] = xs32[s[u] * 16 + c16];
#pragma unroll
        for (int u = 0; u < 8; ++u) {
            accx = fmaf(m[u], bflo(v[u]), accx);
            accy = fmaf(m[u], bfhi(v[u]), accy);
        }
    }
    accx += __shfl_xor(accx, 16, 32);
    accy += __shfl_xor(accy, 16, 32);

    // redistribute (feat 2*c16 / 2*c16+1 on lane c16) -> lane = feature
    float ax = __shfl(accx, lane >> 1, 32);
    float ay = __shfl(accy, lane >> 1, 32);
    float w = -dis[node];
    Lxf[node * 32 + lane] = w * ((lane & 1) ? ay : ax);
}

// ---------------------------------------------------------------------------
// K6: dense per-node math: Z/Ht/H + hw GEMM, output pre-scaled bf16 pairs
//   hws32[node] = pack(bf16(disg*hw))   (ready for k_gout's gather)
// ---------------------------------------------------------------------------
__global__ __launch_bounds__(256) void k_dense(
        const float* __restrict__ x, const float* __restrict__ Lxf,
        const float* __restrict__ W_xz, const float* __restrict__ b_xz,
        const float* __restrict__ b_hz,
        const float* __restrict__ W_xh, const float* __restrict__ b_xh,
        const float* __restrict__ b_hh,
        const float* __restrict__ W_gcn, const float* __restrict__ disg,
        unsigned* __restrict__ hws32) {
    __shared__ float sW[5 * 1024];   // Wz0,Wz1,Wh0,Wh1,Wgcn  (k-major: [k][f])
    __shared__ float sbz[32], sbh[32];
    int tid = threadIdx.x;
    for (int i = tid; i < 2048; i += 256) { sW[i] = W_xz[i]; sW[2048 + i] = W_xh[i]; }
    for (int i = tid; i < 1024; i += 256) { sW[4096 + i] = W_gcn[i]; }
    if (tid < 32) { sbz[tid] = b_xz[tid] + b_hz[tid]; sbh[tid] = b_xh[tid] + b_hh[tid]; }
    __syncthreads();

    int node = blockIdx.x * 8 + (tid >> 5);
    int lane = tid & 31;
    const float* Wz0 = sW;
    const float* Wz1 = sW + 1024;
    const float* Wh0 = sW + 2048;
    const float* Wh1 = sW + 3072;
    const float* Wg  = sW + 4096;

    float xv = x[node * 32 + lane];
    float lv = Lxf[node * 32 + lane];
    float z = sbz[lane], t = sbh[lane];
#pragma unroll
    for (int k = 0; k < 32; ++k) {
        float xk = __shfl(xv, k, 32);
        float lk = __shfl(lv, k, 32);
        z = fmaf(xk, Wz0[k * 32 + lane], z);
        z = fmaf(lk, Wz1[k * 32 + lane], z);
        t = fmaf(xk, Wh0[k * 32 + lane], t);
        t = fmaf(lk, Wh1[k * 32 + lane], t);
    }
    float Z = 1.0f / (1.0f + expf(-z));
    float H = (1.0f - Z) * tanhf(t);

    float hwv = 0.0f;
#pragma unroll
    for (int k = 0; k < 32; ++k) {
        float Hk = __shfl(H, k, 32);
        hwv = fmaf(Hk, Wg[k * 32 + lane], hwv);
    }
    float dgh = disg[node] * hwv;                 // pre-scale by disg[node]
    float h0 = __shfl(dgh, 2 * (lane & 15), 32);
    float h1 = __shfl(dgh, 2 * (lane & 15) + 1, 32);
    if (lane < 16) hws32[node * 16 + lane] = packbf(h0, h1);
}

// ---------------------------------------------------------------------------
// K7: pure gather + epilogue:
//   acc = disg[d] * (sum_e hws[src_e] + hws[d])    (self: disg^2*hw)
//   out = relu(acc + b_gcn) . W_lin + b_lin
// ---------------------------------------------------------------------------
__global__ __launch_bounds__(256) void k_gout(
        const unsigned* __restrict__ hws32,
        const int* __restrict__ csr_s,
        const int* __restrict__ start, const int* __restrict__ cd,
        const float* __restrict__ disg,
        const float* __restrict__ b_gcn,
        const float* __restrict__ W_lin, const float* __restrict__ b_lin,
        float* __restrict__ out) {
    int tid = threadIdx.x;
    int node = blockIdx.x * 8 + (tid >> 5);
    int lane = tid & 31, half = lane >> 4, c16 = lane & 15;
    int st = start[node], cn = cd[node];

    float accx = 0.0f, accy = 0.0f;
    for (int j = 0; j < cn; j += 16) {
        int s[8]; float m[8];
#pragma unroll
        for (int u = 0; u < 8; ++u) {
            int jj = j + 2 * u + half;
            int jc = jj < cn ? jj : cn - 1;
            s[u] = csr_s[st + jc];
            m[u] = jj < cn ? 1.0f : 0.0f;
        }
        unsigned v[8];
#pragma unroll
        for (int u = 0; u < 8; ++u) v[u] = hws32[s[u] * 16 + c16];
#pragma unroll
        for (int u = 0; u < 8; ++u) {
            accx = fmaf(m[u], bflo(v[u]), accx);
            accy = fmaf(m[u], bfhi(v[u]), accy);
        }
    }
    accx += __shfl_xor(accx, 16, 32);
    accy += __shfl_xor(accy, 16, 32);

    unsigned su = hws32[node * 16 + c16];   // self row (pre-scaled)
    accx += bflo(su);
    accy += bfhi(su);
    float dg = disg[node];
    accx *= dg;
    accy *= dg;

    float ax = __shfl(accx, lane >> 1, 32);
    float ay = __shfl(accy, lane >> 1, 32);
    float acc = (lane & 1) ? ay : ax;

    float v = fmaxf(acc + b_gcn[lane], 0.0f) * W_lin[lane];
#pragma unroll
    for (int o = 16; o > 0; o >>= 1) v += __shfl_xor(v, o, 32);
    if (lane == 0) out[node] = v + b_lin[0];
}

extern "C" void kernel_launch(void* const* d_in, const int* in_sizes, int n_in,
                              void* d_out, int out_size, void* d_ws, size_t ws_size,
                              hipStream_t stream) {
    const float* x     = (const float*)d_in[0];
    const int*   ei    = (const int*)d_in[1];
    const int*   src   = ei;
    const int*   dst   = ei + N_EDGES;
    const float* W_xz  = (const float*)d_in[2];
    const float* b_xz  = (const float*)d_in[3];
    const float* b_hz  = (const float*)d_in[5];
    // W_xr/b_xr/W_hr/b_hr (d_in[6..9]) are dead: R only multiplies H0 == 0.
    const float* W_xh  = (const float*)d_in[10];
    const float* b_xh  = (const float*)d_in[11];
    const float* b_hh  = (const float*)d_in[13];
    const float* W_gcn = (const float*)d_in[14];
    const float* b_gcn = (const float*)d_in[15];
    const float* W_lin = (const float*)d_in[16];
    const float* b_lin = (const float*)d_in[17];
    float* out = (float*)d_out;

    // Workspace (words): [cs N][cd N][gcur 4][start N][cursor N][dis N][disg N]
    //                    [xsb 16N][Lxf 32N][hws 16N][csr_s E]  = 70N + E + 4
    int* wsi     = (int*)d_ws;
    int* cs      = wsi;
    int* cd      = cs + N_NODES;
    int* gcur    = cd + N_NODES;
    int* start   = gcur + 4;
    int* cursor  = start + N_NODES;
    float* dis   = (float*)(cursor + N_NODES);
    float* disg  = dis + N_NODES;
    unsigned* xs32  = (unsigned*)(disg + N_NODES);            // 16N uint
    float*    Lxf   = (float*)(xs32 + (size_t)16 * N_NODES);  // 32N f32
    unsigned* hws32 = (unsigned*)(Lxf + (size_t)32 * N_NODES);// 16N uint
    int*      csr_s = (int*)(hws32 + (size_t)16 * N_NODES);   // E

    hipMemsetAsync(cs, 0, (2 * (size_t)N_NODES + 4) * sizeof(int), stream);

    k_deg    <<<(N_EDGES + 255) / 256, 256, 0, stream>>>(src, dst, cs, cd);
    k_alloc  <<<(N_NODES + 255) / 256, 256, 0, stream>>>(cs, cd, gcur, start,
                                                         cursor, dis, disg);
    k_cvt    <<<(N_NODES * 32 + 255) / 256, 256, 0, stream>>>(x, dis, (unsigned short*)xs32);
    k_scatter<<<(N_EDGES + 255) / 256, 256, 0, stream>>>(src, dst, cursor, csr_s);
    k_glx    <<<N_NODES / 8, 256, 0, stream>>>(xs32, csr_s, start, cd, dis, Lxf);
    k_dense  <<<N_NODES / 8, 256, 0, stream>>>(x, Lxf, W_xz, b_xz, b_hz,
                                               W_xh, b_xh, b_hh, W_gcn, disg, hws32);
    k_gout   <<<N_NODES / 8, 256, 0, stream>>>(hws32, csr_s, start, cd, disg,
                                               b_gcn, W_lin, b_lin, out);
}

// Round 6
// 224.420 us; speedup vs baseline: 1.9572x; 1.9572x over previous
//
#include <hip/hip_runtime.h>

#define NN 100000
#define NE 1600000
#define NB 391        // node buckets: node >> 8 (256 nodes/bucket, last=160)
#define NBLK 391      // edge chunks of CHUNK
#define CHUNK 4096

// ---- bf16 helpers (RNE) ----------------------------------------------------
__device__ __forceinline__ float bflo(unsigned u) { return __uint_as_float(u << 16); }
__device__ __forceinline__ float bfhi(unsigned u) { return __uint_as_float(u & 0xffff0000u); }
__device__ __forceinline__ unsigned short f2bf(float f) {
    unsigned u = __float_as_uint(f);
    return (unsigned short)((u + 0x7fff + ((u >> 16) & 1)) >> 16);
}
__device__ __forceinline__ unsigned packbf(float a, float b) {
    return (unsigned)f2bf(a) | ((unsigned)f2bf(b) << 16);
}

// ---------------------------------------------------------------------------
// B1: per-(chunk,bucket) counts via LDS histograms (no global atomics).
// ---------------------------------------------------------------------------
__global__ __launch_bounds__(256) void k_bcount(const int* __restrict__ src,
                                                const int* __restrict__ dst,
                                                int* __restrict__ counts_d,
                                                int* __restrict__ counts_s) {
    __shared__ int hd[NB], hs[NB];
    int tid = threadIdx.x, blk = blockIdx.x;
    for (int i = tid; i < NB; i += 256) { hd[i] = 0; hs[i] = 0; }
    __syncthreads();
    int e0 = blk * CHUNK, ee = min(e0 + CHUNK, NE);
    for (int e = e0 + tid; e < ee; e += 256) {
        atomicAdd(&hd[dst[e] >> 8], 1);
        atomicAdd(&hs[src[e] >> 8], 1);
    }
    __syncthreads();
    for (int i = tid; i < NB; i += 256) {
        counts_d[blk * NB + i] = hd[i];
        counts_s[blk * NB + i] = hs[i];
    }
}

// ---------------------------------------------------------------------------
// B2: per-bucket exclusive scan over chunks (in place) + bucket totals.
// grid 2*NB: first NB blocks scan counts_d, rest counts_s.
// ---------------------------------------------------------------------------
__global__ __launch_bounds__(256) void k_scan(int* __restrict__ counts_d,
                                              int* __restrict__ counts_s,
                                              int* __restrict__ totd,
                                              int* __restrict__ tots) {
    int b = blockIdx.x;
    int* T; int* tot;
    if (b < NB) { T = counts_d; tot = totd; }
    else        { T = counts_s; tot = tots; b -= NB; }
    __shared__ int sd[256];
    int tid = threadIdx.x;
    int carry = 0;
    for (int base = 0; base < NBLK; base += 256) {
        int idx = base + tid;
        int v = (idx < NBLK) ? T[idx * NB + b] : 0;
        sd[tid] = v;
        __syncthreads();
        for (int off = 1; off < 256; off <<= 1) {
            int t = (tid >= off) ? sd[tid - off] : 0;
            __syncthreads();
            sd[tid] += t;
            __syncthreads();
        }
        if (idx < NBLK) T[idx * NB + b] = carry + sd[tid] - v;
        int bt = sd[255];
        __syncthreads();
        carry += bt;
    }
    if (tid == 0) tot[b] = carry;
}

// ---------------------------------------------------------------------------
// B3: exclusive scan of bucket totals -> bucket base (+ sentinel = NE).
// grid 2: block 0 = dst side, block 1 = src side.
// ---------------------------------------------------------------------------
__global__ __launch_bounds__(256) void k_scan2(const int* __restrict__ totd,
                                               int* __restrict__ based,
                                               const int* __restrict__ tots,
                                               int* __restrict__ bases) {
    const int* T = blockIdx.x ? tots : totd;
    int* B = blockIdx.x ? bases : based;
    __shared__ int sd[256];
    int tid = threadIdx.x;
    int carry = 0;
    for (int base = 0; base < NB; base += 256) {
        int idx = base + tid;
        int v = (idx < NB) ? T[idx] : 0;
        sd[tid] = v;
        __syncthreads();
        for (int off = 1; off < 256; off <<= 1) {
            int t = (tid >= off) ? sd[tid - off] : 0;
            __syncthreads();
            sd[tid] += t;
            __syncthreads();
        }
        if (idx < NB) B[idx] = carry + sd[tid] - v;
        int bt = sd[255];
        __syncthreads();
        carry += bt;
    }
    if (tid == 0) B[NB] = carry;   // == NE
}

// ---------------------------------------------------------------------------
// B4: scatter edges into bucketed lists with LDS cursors (no global atomics).
//   dst side: packed u32 = (dst&255)<<17 | src   (src < 2^17)
//   src side: 1 byte = src&255 (only counts needed downstream)
// ---------------------------------------------------------------------------
__global__ __launch_bounds__(256) void k_bscatter(
        const int* __restrict__ src, const int* __restrict__ dst,
        const int* __restrict__ counts_d, const int* __restrict__ counts_s,
        const int* __restrict__ based, const int* __restrict__ bases,
        unsigned* __restrict__ bkd, unsigned char* __restrict__ bks) {
    __shared__ int cud[NB], cus[NB];
    int tid = threadIdx.x, blk = blockIdx.x;
    for (int i = tid; i < NB; i += 256) {
        cud[i] = based[i] + counts_d[blk * NB + i];
        cus[i] = bases[i] + counts_s[blk * NB + i];
    }
    __syncthreads();
    int e0 = blk * CHUNK, ee = min(e0 + CHUNK, NE);
    for (int e = e0 + tid; e < ee; e += 256) {
        int s = src[e], d = dst[e];
        int p = atomicAdd(&cud[d >> 8], 1);
        bkd[p] = ((unsigned)(d & 255) << 17) | (unsigned)s;
        int q = atomicAdd(&cus[s >> 8], 1);
        bks[q] = (unsigned char)(s & 255);
    }
}

// ---------------------------------------------------------------------------
// B5: per-bucket pass: in-degree counts, CSR start, CSR scatter (all LDS).
// ---------------------------------------------------------------------------
__global__ __launch_bounds__(256) void k_p2d(const unsigned* __restrict__ bkd,
                                             const int* __restrict__ based,
                                             int* __restrict__ cd,
                                             int* __restrict__ start,
                                             int* __restrict__ csr_s) {
    __shared__ int hist[256], scn[256];
    int b = blockIdx.x, tid = threadIdx.x;
    hist[tid] = 0;
    __syncthreads();
    int eb = based[b], ee = based[b + 1];
    for (int e = eb + tid; e < ee; e += 256)
        atomicAdd(&hist[bkd[e] >> 17], 1);
    __syncthreads();
    int c = hist[tid];
    scn[tid] = c;
    __syncthreads();
    for (int off = 1; off < 256; off <<= 1) {
        int t = (tid >= off) ? scn[tid - off] : 0;
        __syncthreads();
        scn[tid] += t;
        __syncthreads();
    }
    int excl = scn[tid] - c;
    int node = (b << 8) + tid;
    if (node < NN) { cd[node] = c; start[node] = eb + excl; }
    hist[tid] = eb + excl;        // reuse as cursor
    __syncthreads();
    for (int e = eb + tid; e < ee; e += 256) {
        unsigned pk = bkd[e];
        int p = atomicAdd(&hist[pk >> 17], 1);
        csr_s[p] = (int)(pk & 0x1FFFFu);
    }
}

// ---------------------------------------------------------------------------
// B6: per-bucket out-degree counts from byte list.
// ---------------------------------------------------------------------------
__global__ __launch_bounds__(256) void k_p2s(const unsigned char* __restrict__ bks,
                                             const int* __restrict__ bases,
                                             int* __restrict__ cs) {
    __shared__ int hist[256];
    int b = blockIdx.x, tid = threadIdx.x;
    hist[tid] = 0;
    __syncthreads();
    int eb = bases[b], ee = bases[b + 1];
    for (int e = eb + tid; e < ee; e += 256)
        atomicAdd(&hist[bks[e]], 1);
    __syncthreads();
    int node = (b << 8) + tid;
    if (node < NN) cs[node] = hist[tid];
}

// ---------------------------------------------------------------------------
// K_norm: dis = outdeg>0 ? rsqrt(outdeg) : 0 ;  disg = rsqrt(indeg+1)
// ---------------------------------------------------------------------------
__global__ __launch_bounds__(256) void k_norm(const int* __restrict__ cs,
                                              const int* __restrict__ cd,
                                              float* __restrict__ dis,
                                              float* __restrict__ disg) {
    int i = blockIdx.x * 256 + threadIdx.x;
    if (i < NN) {
        int c = cs[i], d = cd[i];
        dis[i]  = c > 0 ? rsqrtf((float)c) : 0.0f;
        disg[i] = rsqrtf((float)d + 1.0f);
    }
}

// ---------------------------------------------------------------------------
// K_cvt: pre-scaled bf16 rows  xsb[s*32+f] = bf16(dis[s]*x[s*32+f])
// ---------------------------------------------------------------------------
__global__ __launch_bounds__(256) void k_cvt(const float* __restrict__ x,
                                             const float* __restrict__ dis,
                                             unsigned short* __restrict__ xsb) {
    int i = blockIdx.x * 256 + threadIdx.x;
    if (i < NN * 32) xsb[i] = f2bf(x[i] * dis[i >> 5]);
}

// ---------------------------------------------------------------------------
// K_node (FUSED): register gather of Lx + GRU GEMMs + GCN weight GEMM.
// ---------------------------------------------------------------------------
__global__ __launch_bounds__(256) void k_node(
        const float* __restrict__ x, const unsigned* __restrict__ xs32,
        const int* __restrict__ csr_s,
        const int* __restrict__ start, const int* __restrict__ cd,
        const float* __restrict__ dis, const float* __restrict__ disg,
        const float* __restrict__ W_xz, const float* __restrict__ b_xz,
        const float* __restrict__ b_hz,
        const float* __restrict__ W_xh, const float* __restrict__ b_xh,
        const float* __restrict__ b_hh,
        const float* __restrict__ W_gcn,
        unsigned* __restrict__ hws32) {
    __shared__ float sW[5 * 1024];   // Wz0,Wz1,Wh0,Wh1,Wgcn  (k-major: [k][f])
    __shared__ float sbz[32], sbh[32];
    int tid = threadIdx.x;
    for (int i = tid; i < 2048; i += 256) { sW[i] = W_xz[i]; sW[2048 + i] = W_xh[i]; }
    for (int i = tid; i < 1024; i += 256) { sW[4096 + i] = W_gcn[i]; }
    if (tid < 32) { sbz[tid] = b_xz[tid] + b_hz[tid]; sbh[tid] = b_xh[tid] + b_hh[tid]; }
    __syncthreads();

    int node = blockIdx.x * 8 + (tid >> 5);
    int lane = tid & 31, half = lane >> 4, c16 = lane & 15;
    int st = start[node], cn = cd[node];

    // batched bf16 gather: 8 uint loads/lane = 16 rows in flight
    float accx = 0.0f, accy = 0.0f;
    for (int j = 0; j < cn; j += 16) {
        int s[8]; float m[8];
#pragma unroll
        for (int u = 0; u < 8; ++u) {
            int jj = j + 2 * u + half;
            int jc = jj < cn ? jj : cn - 1;
            s[u] = csr_s[st + jc];
            m[u] = jj < cn ? 1.0f : 0.0f;
        }
        unsigned v[8];
#pragma unroll
        for (int u = 0; u < 8; ++u) v[u] = xs32[s[u] * 16 + c16];
#pragma unroll
        for (int u = 0; u < 8; ++u) {
            accx = fmaf(m[u], bflo(v[u]), accx);
            accy = fmaf(m[u], bfhi(v[u]), accy);
        }
    }
    accx += __shfl_xor(accx, 16, 32);
    accy += __shfl_xor(accy, 16, 32);
    float ax = __shfl(accx, lane >> 1, 32);
    float ay = __shfl(accy, lane >> 1, 32);
    float lv = -dis[node] * ((lane & 1) ? ay : ax);   // lane = feature

    const float* Wz0 = sW;
    const float* Wz1 = sW + 1024;
    const float* Wh0 = sW + 2048;
    const float* Wh1 = sW + 3072;
    const float* Wg  = sW + 4096;

    float xv = x[node * 32 + lane];
    float z = sbz[lane], t = sbh[lane];
#pragma unroll
    for (int k = 0; k < 32; ++k) {
        float xk = __shfl(xv, k, 32);
        float lk = __shfl(lv, k, 32);
        z = fmaf(xk, Wz0[k * 32 + lane], z);
        z = fmaf(lk, Wz1[k * 32 + lane], z);
        t = fmaf(xk, Wh0[k * 32 + lane], t);
        t = fmaf(lk, Wh1[k * 32 + lane], t);
    }
    float Z = 1.0f / (1.0f + expf(-z));
    float H = (1.0f - Z) * tanhf(t);

    float hwv = 0.0f;
#pragma unroll
    for (int k = 0; k < 32; ++k) {
        float Hk = __shfl(H, k, 32);
        hwv = fmaf(Hk, Wg[k * 32 + lane], hwv);
    }
    float dgh = disg[node] * hwv;                 // pre-scale by disg[node]
    float h0 = __shfl(dgh, 2 * c16, 32);
    float h1 = __shfl(dgh, 2 * c16 + 1, 32);
    if (lane < 16) hws32[node * 16 + lane] = packbf(h0, h1);
}

// ---------------------------------------------------------------------------
// K_gout: pure gather + epilogue (unchanged from R5, passing).
// ---------------------------------------------------------------------------
__global__ __launch_bounds__(256) void k_gout(
        const unsigned* __restrict__ hws32,
        const int* __restrict__ csr_s,
        const int* __restrict__ start, const int* __restrict__ cd,
        const float* __restrict__ disg,
        const float* __restrict__ b_gcn,
        const float* __restrict__ W_lin, const float* __restrict__ b_lin,
        float* __restrict__ out) {
    int tid = threadIdx.x;
    int node = blockIdx.x * 8 + (tid >> 5);
    int lane = tid & 31, half = lane >> 4, c16 = lane & 15;
    int st = start[node], cn = cd[node];

    float accx = 0.0f, accy = 0.0f;
    for (int j = 0; j < cn; j += 16) {
        int s[8]; float m[8];
#pragma unroll
        for (int u = 0; u < 8; ++u) {
            int jj = j + 2 * u + half;
            int jc = jj < cn ? jj : cn - 1;
            s[u] = csr_s[st + jc];
            m[u] = jj < cn ? 1.0f : 0.0f;
        }
        unsigned v[8];
#pragma unroll
        for (int u = 0; u < 8; ++u) v[u] = hws32[s[u] * 16 + c16];
#pragma unroll
        for (int u = 0; u < 8; ++u) {
            accx = fmaf(m[u], bflo(v[u]), accx);
            accy = fmaf(m[u], bfhi(v[u]), accy);
        }
    }
    accx += __shfl_xor(accx, 16, 32);
    accy += __shfl_xor(accy, 16, 32);

    unsigned su = hws32[node * 16 + c16];   // self row (pre-scaled)
    accx += bflo(su);
    accy += bfhi(su);
    float dg = disg[node];
    accx *= dg;
    accy *= dg;

    float ax = __shfl(accx, lane >> 1, 32);
    float ay = __shfl(accy, lane >> 1, 32);
    float acc = (lane & 1) ? ay : ax;

    float v = fmaxf(acc + b_gcn[lane], 0.0f) * W_lin[lane];
#pragma unroll
    for (int o = 16; o > 0; o >>= 1) v += __shfl_xor(v, o, 32);
    if (lane == 0) out[node] = v + b_lin[0];
}

extern "C" void kernel_launch(void* const* d_in, const int* in_sizes, int n_in,
                              void* d_out, int out_size, void* d_ws, size_t ws_size,
                              hipStream_t stream) {
    const float* x     = (const float*)d_in[0];
    const int*   ei    = (const int*)d_in[1];
    const int*   src   = ei;
    const int*   dst   = ei + NE;
    const float* W_xz  = (const float*)d_in[2];
    const float* b_xz  = (const float*)d_in[3];
    const float* b_hz  = (const float*)d_in[5];
    // W_xr/b_xr/W_hr/b_hr (d_in[6..9]) are dead: R only multiplies H0 == 0.
    const float* W_xh  = (const float*)d_in[10];
    const float* b_xh  = (const float*)d_in[11];
    const float* b_hh  = (const float*)d_in[13];
    const float* W_gcn = (const float*)d_in[14];
    const float* b_gcn = (const float*)d_in[15];
    const float* W_lin = (const float*)d_in[16];
    const float* b_lin = (const float*)d_in[17];
    float* out = (float*)d_out;

    // Workspace (4B words). No memsets needed: every array is fully written
    // before read by the pipeline.
    int* w = (int*)d_ws;
    int* counts_d = w;                    w += 160000;          // NBLK*NB=152881
    int* counts_s = w;                    w += 160000;
    int* totd     = w;                    w += 512;             // NB
    int* tots     = w;                    w += 512;
    int* based    = w;                    w += 512;             // NB+1
    int* bases    = w;                    w += 512;
    int* cs       = w;                    w += NN;
    int* cd       = w;                    w += NN;
    int* start    = w;                    w += NN;
    float* dis    = (float*)w;            w += NN;
    float* disg   = (float*)w;            w += NN;
    unsigned* xs32  = (unsigned*)w;       w += 16 * NN;         // bf16 pairs
    unsigned* hws32 = (unsigned*)w;       w += 16 * NN;
    unsigned* bkd   = (unsigned*)w;       w += NE;              // packed dst-bucket list
    unsigned char* bks = (unsigned char*)w; w += NE / 4;        // byte src-bucket list
    int* csr_s    = w;                    w += NE;

    k_bcount  <<<NBLK, 256, 0, stream>>>(src, dst, counts_d, counts_s);
    k_scan    <<<2 * NB, 256, 0, stream>>>(counts_d, counts_s, totd, tots);
    k_scan2   <<<2, 256, 0, stream>>>(totd, based, tots, bases);
    k_bscatter<<<NBLK, 256, 0, stream>>>(src, dst, counts_d, counts_s,
                                         based, bases, bkd, bks);
    k_p2d     <<<NB, 256, 0, stream>>>(bkd, based, cd, start, csr_s);
    k_p2s     <<<NB, 256, 0, stream>>>(bks, bases, cs);
    k_norm    <<<(NN + 255) / 256, 256, 0, stream>>>(cs, cd, dis, disg);
    k_cvt     <<<(NN * 32 + 255) / 256, 256, 0, stream>>>(x, dis, (unsigned short*)xs32);
    k_node    <<<NN / 8, 256, 0, stream>>>(x, xs32, csr_s, start, cd, dis, disg,
                                           W_xz, b_xz, b_hz, W_xh, b_xh, b_hh,
                                           W_gcn, hws32);
    k_gout    <<<NN / 8, 256, 0, stream>>>(hws32, csr_s, start, cd, disg,
                                           b_gcn, W_lin, b_lin, out);
}